// Round 1
// 647.047 us; speedup vs baseline: 1.0155x; 1.0155x over previous
//
#include <hip/hip_runtime.h>
#include <math.h>

#define N_BATCH 1000000
#define FEAT4 32                               // 128 floats = 32 float4
#define GRID_MAIN 2048
#define BLOCK_MAIN 256
#define GROUPS_PER_BLOCK 8                     // 256 threads / 32 lanes
#define N_GROUPS (GRID_MAIN * GROUPS_PER_BLOCK)  // 16384
#define RPC 8                                  // rows per chunk (1e6 % 8 == 0, no tail)
#define N_CHUNKS (N_BATCH / RPC)               // 125000

// Zero the scalar output so nh_main can accumulate with atomics.
// (Replaces the workspace-partials path entirely: this experiment tests
//  whether avoiding d_ws removes the ~313 us 2GB workspace-poison fill.)
__global__ void nh_init(float* __restrict__ out) { out[0] = 0.0f; }

__global__ __launch_bounds__(BLOCK_MAIN)
void nh_main(const float4* __restrict__ x,
             const int* __restrict__ labels,
             const float4* __restrict__ centers,
             float* __restrict__ out) {
    const int lane32 = threadIdx.x & 31;
    const int gid = blockIdx.x * GROUPS_PER_BLOCK + (threadIdx.x >> 5);

    // margin = ||c0 - c1|| / 10, recomputed redundantly per wave.
    // 256 B from L2 per wave + 5 shuffles — removes the nh_precompute
    // kernel and the margin round-trip through the workspace.
    {
    }
    float4 a = centers[lane32];                // row 0, both wave halves
    float4 b = centers[FEAT4 + lane32];        // row 1
    float d = a.x - b.x; float ms = d * d;
    d = a.y - b.y; ms = fmaf(d, d, ms);
    d = a.z - b.z; ms = fmaf(d, d, ms);
    d = a.w - b.w; ms = fmaf(d, d, ms);
    #pragma unroll
    for (int m = 16; m >= 1; m >>= 1) ms += __shfl_xor(ms, m);
    const float margin = sqrtf(ms) * 0.1f;

    float local = 0.0f;

    // 8 consecutive rows per 32-lane group per iteration:
    //  - 4 KB contiguous x-traffic in flight per group (32 KB per block-iter)
    //  - 8 independent label->center gather chains
    //  - 8 ILP-parallel butterfly reduction chains (vs 2 before)
    for (int c = gid; c < N_CHUNKS; c += N_GROUPS) {
        const int r0 = c * RPC;

        const int* lp = labels + r0;
        int lab[RPC];
        #pragma unroll
        for (int j = 0; j < RPC; ++j) lab[j] = lp[j];

        const float4* xp = x + (size_t)r0 * FEAT4 + lane32;
        float4 xv[RPC];
        #pragma unroll
        for (int j = 0; j < RPC; ++j) xv[j] = xp[j * FEAT4];

        float4 cv[RPC];
        #pragma unroll
        for (int j = 0; j < RPC; ++j) cv[j] = centers[lab[j] * FEAT4 + lane32];

        float s[RPC];
        #pragma unroll
        for (int j = 0; j < RPC; ++j) {
            float t0 = xv[j].x - cv[j].x; float t = t0 * t0;
            t0 = xv[j].y - cv[j].y; t = fmaf(t0, t0, t);
            t0 = xv[j].z - cv[j].z; t = fmaf(t0, t0, t);
            t0 = xv[j].w - cv[j].w; t = fmaf(t0, t0, t);
            s[j] = t;
        }

        // 8 independent 32-lane reductions, 5 steps each, fully ILP-overlapped
        #pragma unroll
        for (int m = 16; m >= 1; m >>= 1) {
            #pragma unroll
            for (int j = 0; j < RPC; ++j) s[j] += __shfl_xor(s[j], m);
        }

        if (lane32 == 0) {
            #pragma unroll
            for (int j = 0; j < RPC; ++j) {
                float h = s[j] - margin;
                local += (h > 0.0f) ? h : 0.0f;
            }
        }
    }

    // block reduction, then ONE device-scope atomic per block onto out[0]
    #pragma unroll
    for (int m = 32; m >= 1; m >>= 1) local += __shfl_xor(local, m);
    __shared__ float wavesum[BLOCK_MAIN / 64];
    if ((threadIdx.x & 63) == 0) wavesum[threadIdx.x >> 6] = local;
    __syncthreads();
    if (threadIdx.x == 0) {
        float t = 0.0f;
        #pragma unroll
        for (int w = 0; w < BLOCK_MAIN / 64; ++w) t += wavesum[w];
        atomicAdd(out, t * (1.0f / ((float)N_BATCH * 4.0f)));
    }
}

extern "C" void kernel_launch(void* const* d_in, const int* in_sizes, int n_in,
                              void* d_out, int out_size, void* d_ws, size_t ws_size,
                              hipStream_t stream) {
    const float* x       = (const float*)d_in[0];   // (1e6, 128) fp32
    const int*   labels  = (const int*)d_in[1];     // (1e6,) int32
    const float* centers = (const float*)d_in[2];   // (1000, 128) fp32
    float* out = (float*)d_out;

    // NOTE: d_ws deliberately untouched this round (fill-elimination experiment).
    nh_init<<<1, 1, 0, stream>>>(out);
    nh_main<<<GRID_MAIN, BLOCK_MAIN, 0, stream>>>(
        (const float4*)x, labels, (const float4*)centers, out);
}

// Round 2
// 620.706 us; speedup vs baseline: 1.0586x; 1.0424x over previous
//
#include <hip/hip_runtime.h>
#include <math.h>

#define N_BATCH 1000000
#define FEAT4 32                                 // 128 floats = 32 float4
#define GRID_MAIN 2048
#define BLOCK_MAIN 256
#define GROUPS_PER_BLOCK 8                       // 256 threads / 32 lanes
#define N_GROUPS (GRID_MAIN * GROUPS_PER_BLOCK)  // 16384
#define RPC 8                                    // rows per chunk (1e6 % 8 == 0)
#define N_CHUNKS (N_BATCH / RPC)                 // 125000

typedef float f4 __attribute__((ext_vector_type(4)));

// Zero the scalar output so nh_main can accumulate with one atomic per block.
__global__ void nh_init(float* __restrict__ out) { out[0] = 0.0f; }

__global__ __launch_bounds__(BLOCK_MAIN)
void nh_main(const f4* __restrict__ x,
             const int* __restrict__ labels,
             const f4* __restrict__ centers,
             float* __restrict__ out) {
    const int lane32 = threadIdx.x & 31;
    const int gid = blockIdx.x * GROUPS_PER_BLOCK + (threadIdx.x >> 5);

    // margin = ||c0 - c1|| / 10, recomputed redundantly per wave (L2-resident rows).
    {
        f4 a = centers[lane32];
        f4 b = centers[FEAT4 + lane32];
        float d = a.x - b.x; float ms = d * d;
        d = a.y - b.y; ms = fmaf(d, d, ms);
        d = a.z - b.z; ms = fmaf(d, d, ms);
        d = a.w - b.w; ms = fmaf(d, d, ms);
        #pragma unroll
        for (int m = 16; m >= 1; m >>= 1) ms += __shfl_xor(ms, m);
        float margin_ = sqrtf(ms) * 0.1f;
        // keep in a named var below via copy (avoids shadowing issues)
        __shared__ float dummy; (void)dummy;
        // fallthrough: margin_ captured below
        float local = 0.0f;

        // ---- software-pipelined main loop ----
        // Per-group trip count is only ~8 (125000 chunks / 16384 groups), so a
        // 1-deep label pipeline is cheap. Labels for chunk c are loaded during
        // chunk c-1's compute, so the center gather issues with ZERO wait at
        // loop top — the label HBM-miss latency (~900 cyc) is fully absorbed.
        int c = gid;
        int lab[RPC];
        if (c < N_CHUNKS) {
            const int* lp = labels + c * RPC;
            #pragma unroll
            for (int j = 0; j < RPC; ++j) lab[j] = __builtin_nontemporal_load(lp + j);
        }

        for (; c < N_CHUNKS; c += N_GROUPS) {
            const int cn = c + N_GROUPS;

            // 1) center gathers for CURRENT chunk — labels already in registers
            f4 cv[RPC];
            #pragma unroll
            for (int j = 0; j < RPC; ++j) cv[j] = centers[lab[j] * FEAT4 + lane32];

            // 2) x loads for CURRENT chunk — nontemporal: pure single-touch
            //    stream, keep L2 clean for the centers table
            const f4* xp = x + (size_t)c * RPC * FEAT4 + lane32;
            f4 xv[RPC];
            #pragma unroll
            for (int j = 0; j < RPC; ++j)
                xv[j] = __builtin_nontemporal_load(xp + j * FEAT4);

            // 3) prefetch NEXT chunk's labels (breaks label->gather serial chain)
            int labn[RPC];
            if (cn < N_CHUNKS) {
                const int* lpn = labels + cn * RPC;
                #pragma unroll
                for (int j = 0; j < RPC; ++j)
                    labn[j] = __builtin_nontemporal_load(lpn + j);
            }

            // 4) compute 8 per-row squared distances (ILP-parallel)
            float s[RPC];
            #pragma unroll
            for (int j = 0; j < RPC; ++j) {
                float t0 = xv[j].x - cv[j].x; float t = t0 * t0;
                t0 = xv[j].y - cv[j].y; t = fmaf(t0, t0, t);
                t0 = xv[j].z - cv[j].z; t = fmaf(t0, t0, t);
                t0 = xv[j].w - cv[j].w; t = fmaf(t0, t0, t);
                s[j] = t;
            }

            // 5) 8 independent 32-lane butterflies, ILP-overlapped
            #pragma unroll
            for (int m = 16; m >= 1; m >>= 1) {
                #pragma unroll
                for (int j = 0; j < RPC; ++j) s[j] += __shfl_xor(s[j], m);
            }

            if (lane32 == 0) {
                #pragma unroll
                for (int j = 0; j < RPC; ++j) {
                    float h = s[j] - margin_;
                    local += (h > 0.0f) ? h : 0.0f;
                }
            }

            // rotate the label pipeline (dead values if cn >= N_CHUNKS)
            #pragma unroll
            for (int j = 0; j < RPC; ++j) lab[j] = labn[j];
        }

        // block reduction, then ONE device-scope atomic per block
        #pragma unroll
        for (int m = 32; m >= 1; m >>= 1) local += __shfl_xor(local, m);
        __shared__ float wavesum[BLOCK_MAIN / 64];
        if ((threadIdx.x & 63) == 0) wavesum[threadIdx.x >> 6] = local;
        __syncthreads();
        if (threadIdx.x == 0) {
            float t = 0.0f;
            #pragma unroll
            for (int w = 0; w < BLOCK_MAIN / 64; ++w) t += wavesum[w];
            atomicAdd(out, t * (1.0f / ((float)N_BATCH * 4.0f)));
        }
    }
}

extern "C" void kernel_launch(void* const* d_in, const int* in_sizes, int n_in,
                              void* d_out, int out_size, void* d_ws, size_t ws_size,
                              hipStream_t stream) {
    const float* x       = (const float*)d_in[0];   // (1e6, 128) fp32
    const int*   labels  = (const int*)d_in[1];     // (1e6,) int32
    const float* centers = (const float*)d_in[2];   // (1000, 128) fp32
    float* out = (float*)d_out;

    nh_init<<<1, 1, 0, stream>>>(out);
    nh_main<<<GRID_MAIN, BLOCK_MAIN, 0, stream>>>(
        (const f4*)x, labels, (const f4*)centers, out);
}